// Round 1
// baseline (411.221 us; speedup 1.0000x reference)
//
#include <hip/hip_runtime.h>
#include <math.h>

#define Bq 32
#define Sq 2048
#define Dq 1024
#define Tq 8

// ---------------------------------------------------------------------------
// Kernel 1: scores[b,s] = dot(qry[b,:], ctx[b,s,:]) + log(mask[b,s])
// Grid: (S/16, B), block 256 (4 waves). Each wave computes 4 rows.
// Lane l reads float4 index (l + 64k), k=0..3 -> covers D=1024 floats.
// ---------------------------------------------------------------------------
__global__ __launch_bounds__(256) void scores_kernel(
    const float* __restrict__ qry, const float* __restrict__ ctx,
    const float* __restrict__ mask, float* __restrict__ scores)
{
    const int b      = blockIdx.y;
    const int s_base = blockIdx.x * 16;
    const int wave   = threadIdx.x >> 6;
    const int lane   = threadIdx.x & 63;

    const float4* q4 = (const float4*)(qry + (size_t)b * Dq);
    float4 q[4];
#pragma unroll
    for (int k = 0; k < 4; ++k) q[k] = q4[lane + 64 * k];

#pragma unroll
    for (int r = 0; r < 4; ++r) {
        const int s = s_base + wave * 4 + r;
        const float4* c4 = (const float4*)(ctx + ((size_t)b * Sq + s) * Dq);
        float acc = 0.f;
#pragma unroll
        for (int k = 0; k < 4; ++k) {
            float4 c = c4[lane + 64 * k];
            acc += q[k].x * c.x + q[k].y * c.y + q[k].z * c.z + q[k].w * c.w;
        }
#pragma unroll
        for (int off = 32; off >= 1; off >>= 1)
            acc += __shfl_down(acc, off, 64);
        if (lane == 0)
            scores[(size_t)b * Sq + s] = acc + logf(mask[(size_t)b * Sq + s]);
    }
}

// ---------------------------------------------------------------------------
// Kernel 2: softmax over S per row, then alphas = min(parent_alphas, softmax).
// Grid: (B), block 256. Each thread owns 8 s-positions.
// ---------------------------------------------------------------------------
__global__ __launch_bounds__(256) void softmax_min_kernel(
    const float* __restrict__ scores, const float* __restrict__ prevatts,
    const int* __restrict__ parent_ptr, float* __restrict__ alphas)
{
    const int b = blockIdx.x;
    const int t = threadIdx.x;
    __shared__ float redmax[4];
    __shared__ float redsum[4];

    const float* srow = scores + (size_t)b * Sq;
    float vals[8];
    float m = -INFINITY;
#pragma unroll
    for (int i = 0; i < 8; ++i) {
        vals[i] = srow[t + 256 * i];
        m = fmaxf(m, vals[i]);
    }
#pragma unroll
    for (int off = 32; off >= 1; off >>= 1)
        m = fmaxf(m, __shfl_down(m, off, 64));
    if ((t & 63) == 0) redmax[t >> 6] = m;
    __syncthreads();
    m = fmaxf(fmaxf(redmax[0], redmax[1]), fmaxf(redmax[2], redmax[3]));

    float sum = 0.f;
#pragma unroll
    for (int i = 0; i < 8; ++i) {
        vals[i] = expf(vals[i] - m);
        sum += vals[i];
    }
#pragma unroll
    for (int off = 32; off >= 1; off >>= 1)
        sum += __shfl_down(sum, off, 64);
    if ((t & 63) == 0) redsum[t >> 6] = sum;
    __syncthreads();
    sum = redsum[0] + redsum[1] + redsum[2] + redsum[3];
    const float inv = 1.0f / sum;

    const float* par = prevatts + ((size_t)b * Tq + parent_ptr[b]) * Sq;
#pragma unroll
    for (int i = 0; i < 8; ++i) {
        const int s = t + 256 * i;
        alphas[(size_t)b * Sq + s] = fminf(par[s], vals[i] * inv);
    }
}

// ---------------------------------------------------------------------------
// Kernel 3: summary[b,d] = sum_s alphas[b,s] * ctx[b,s,d]
// Grid: (S/128, B), block 256. Thread t owns columns [4t, 4t+4). Each block
// accumulates a 128-row slice of S, then atomicAdds into summary (zeroed).
// ---------------------------------------------------------------------------
__global__ __launch_bounds__(256) void summary_kernel(
    const float* __restrict__ ctx, const float* __restrict__ alphas,
    float* __restrict__ summary)
{
    const int b      = blockIdx.y;
    const int s_base = blockIdx.x * 128;
    const int t      = threadIdx.x;

    __shared__ float la[128];
    if (t < 128) la[t] = alphas[(size_t)b * Sq + s_base + t];
    __syncthreads();

    const float4* c4 = (const float4*)(ctx + ((size_t)b * Sq + s_base) * Dq);
    float4 acc = make_float4(0.f, 0.f, 0.f, 0.f);
    for (int s = 0; s < 128; ++s) {
        const float a = la[s];
        float4 c = c4[(size_t)s * (Dq / 4) + t];
        acc.x += a * c.x;
        acc.y += a * c.y;
        acc.z += a * c.z;
        acc.w += a * c.w;
    }
    float* out = summary + (size_t)b * Dq + t * 4;
    atomicAdd(out + 0, acc.x);
    atomicAdd(out + 1, acc.y);
    atomicAdd(out + 2, acc.z);
    atomicAdd(out + 3, acc.w);
}

extern "C" void kernel_launch(void* const* d_in, const int* in_sizes, int n_in,
                              void* d_out, int out_size, void* d_ws, size_t ws_size,
                              hipStream_t stream)
{
    const float* qry        = (const float*)d_in[0];
    const float* ctx        = (const float*)d_in[1];
    const float* mask       = (const float*)d_in[2];
    const float* prevatts   = (const float*)d_in[3];
    const int*   parent_ptr = (const int*)d_in[4];

    float* out     = (float*)d_out;
    float* alphas  = out;                  // B*S = 65536
    float* summary = out + Bq * Sq;        // B*D = 32768
    float* scores  = out + Bq * Sq + Bq * Dq; // B*S = 65536

    // summary is atomically accumulated -> must start at zero (d_out is
    // poisoned to 0xAA before every timed launch).
    hipMemsetAsync(summary, 0, (size_t)Bq * Dq * sizeof(float), stream);

    scores_kernel<<<dim3(Sq / 16, Bq), 256, 0, stream>>>(qry, ctx, mask, scores);
    softmax_min_kernel<<<Bq, 256, 0, stream>>>(scores, prevatts, parent_ptr, alphas);
    summary_kernel<<<dim3(Sq / 128, Bq), 256, 0, stream>>>(ctx, alphas, summary);
}